// Round 1
// baseline (12.625 us; speedup 1.0000x reference)
//
#include <hip/hip_runtime.h>
#include <hip/hip_bf16.h>

// Embedding gather: out[b,s,:] = table[idx[b,s], :]
// idx: [128,512] int32, table: [3882,128] f32, out: [128,512,128] f32
// Each thread handles one float4 (4 floats) of an output row; 32 float4 per row.

__global__ __launch_bounds__(256) void embed_gather_kernel(
    const int* __restrict__ idx,      // 65536 indices
    const float4* __restrict__ tab4,  // 3882 * 32 float4
    float4* __restrict__ out4,        // 65536 * 32 float4
    int total4)                       // 65536 * 32
{
    int stride = gridDim.x * blockDim.x;
    for (int i = blockIdx.x * blockDim.x + threadIdx.x; i < total4; i += stride) {
        int row = i >> 5;          // which token
        int col = i & 31;          // which float4 within the 128-float row
        int e = idx[row];          // broadcast within each 32-lane group (L1-cached)
        out4[i] = tab4[(long)e * 32 + col];
    }
}

extern "C" void kernel_launch(void* const* d_in, const int* in_sizes, int n_in,
                              void* d_out, int out_size, void* d_ws, size_t ws_size,
                              hipStream_t stream) {
    const int* idx = (const int*)d_in[0];
    const float4* tab4 = (const float4*)d_in[1];
    float4* out4 = (float4*)d_out;

    const int total4 = (128 * 512) * (128 / 4);   // 2,097,152
    const int block = 256;
    int grid = 2048;                               // grid-stride; ~8 blocks/CU
    embed_gather_kernel<<<grid, block, 0, stream>>>(idx, tab4, out4, total4);
}

// Round 2
// 12.523 us; speedup vs baseline: 1.0082x; 1.0082x over previous
//
#include <hip/hip_runtime.h>
#include <hip/hip_bf16.h>

// Embedding gather: out[b,s,:] = table[idx[b,s], :]
// idx: [128,512] int32, table: [3882,128] f32, out: [128,512,128] f32
//
// One-shot, no grid-stride loop. 8 threads per output row; each thread
// loads idx once, then issues 4 independent float4 gathers + 4 coalesced
// float4 stores (thread j of a row handles float4 j, j+8, j+16, j+24 so
// consecutive lanes touch consecutive 16B segments).

__global__ __launch_bounds__(256) void embed_gather_kernel(
    const int* __restrict__ idx,      // 65536 indices
    const float4* __restrict__ tab4,  // 3882 * 32 float4
    float4* __restrict__ out4)        // 65536 * 32 float4
{
    int t = blockIdx.x * 256 + threadIdx.x;   // 0 .. 524287
    int row = t >> 3;                          // 8 threads per row
    int col = t & 7;

    int e = idx[row];                          // broadcast within 8-lane group
    long tbase = (long)e * 32 + col;
    long obase = (long)row * 32 + col;

    // 4 independent gathers — overlapped in flight
    float4 a = tab4[tbase];
    float4 b = tab4[tbase + 8];
    float4 c = tab4[tbase + 16];
    float4 d = tab4[tbase + 24];

    out4[obase]      = a;
    out4[obase + 8]  = b;
    out4[obase + 16] = c;
    out4[obase + 24] = d;
}

extern "C" void kernel_launch(void* const* d_in, const int* in_sizes, int n_in,
                              void* d_out, int out_size, void* d_ws, size_t ws_size,
                              hipStream_t stream) {
    const int* idx = (const int*)d_in[0];
    const float4* tab4 = (const float4*)d_in[1];
    float4* out4 = (float4*)d_out;

    // 65536 rows * 8 threads/row = 524288 threads = 2048 blocks * 256
    embed_gather_kernel<<<2048, 256, 0, stream>>>(idx, tab4, out4);
}

// Round 4
// 11.891 us; speedup vs baseline: 1.0617x; 1.0531x over previous
//
#include <hip/hip_runtime.h>
#include <hip/hip_bf16.h>

// Embedding gather: out[b,s,:] = table[idx[b,s], :]
// idx: [128,512] int32, table: [3882,128] f32, out: [128,512,128] f32
//
// 8 threads per output row; each thread: 1 idx load, 4 independent float4
// gathers (L2-resident table), 4 nontemporal 16B stores (write-once
// stream — keep it OUT of L2 so the table stays resident).
//
// Use a clang ext_vector type: __builtin_nontemporal_* rejects HIP's
// HIP_vector_type<float,4> but accepts native vectors.

typedef float f32x4 __attribute__((ext_vector_type(4)));

__global__ __launch_bounds__(256) void embed_gather_kernel(
    const int* __restrict__ idx,       // 65536 indices
    const f32x4* __restrict__ tab4,    // 3882 * 32 float4
    f32x4* __restrict__ out4)          // 65536 * 32 float4
{
    int t = blockIdx.x * 256 + threadIdx.x;   // 0 .. 524287
    int row = t >> 3;                          // 8 threads per row
    int col = t & 7;

    int e = __builtin_nontemporal_load(&idx[row]);   // read-once stream
    const f32x4* __restrict__ src = tab4 + (size_t)e * 32 + col;
    f32x4* __restrict__ dst = out4 + (size_t)row * 32 + col;

    // 4 independent gathers in flight
    f32x4 a = src[0];
    f32x4 b = src[8];
    f32x4 c = src[16];
    f32x4 d = src[24];

    // write-once output: nontemporal, don't thrash L2
    __builtin_nontemporal_store(a, &dst[0]);
    __builtin_nontemporal_store(b, &dst[8]);
    __builtin_nontemporal_store(c, &dst[16]);
    __builtin_nontemporal_store(d, &dst[24]);
}

extern "C" void kernel_launch(void* const* d_in, const int* in_sizes, int n_in,
                              void* d_out, int out_size, void* d_ws, size_t ws_size,
                              hipStream_t stream) {
    const int* idx = (const int*)d_in[0];
    const f32x4* tab4 = (const f32x4*)d_in[1];
    f32x4* out4 = (f32x4*)d_out;

    // 65536 rows * 8 threads/row = 524288 threads = 2048 blocks * 256
    embed_gather_kernel<<<2048, 256, 0, stream>>>(idx, tab4, out4);
}

// Round 5
// 11.731 us; speedup vs baseline: 1.0762x; 1.0136x over previous
//
#include <hip/hip_runtime.h>
#include <hip/hip_bf16.h>

// Embedding gather: out[b,s,:] = table[idx[b,s], :]
// idx: [128,512] int32, table: [3882,128] f32, out: [128,512,128] f32
//
// 2 rows per thread: 2 independent idx loads -> 8 independent float4
// gathers -> 8 nontemporal stores. Maximizes memory-level parallelism
// per wave while keeping stores full-128B-line coalesced.

typedef float f32x4 __attribute__((ext_vector_type(4)));

__global__ __launch_bounds__(256) void embed_gather_kernel(
    const int* __restrict__ idx,       // 65536 indices
    const f32x4* __restrict__ tab4,    // 3882 * 32 float4
    f32x4* __restrict__ out4)          // 65536 * 32 float4
{
    int t = blockIdx.x * 256 + threadIdx.x;   // 0 .. 262143
    int col = t & 7;                           // float4 slot 0..7
    int r0 = (t >> 3) * 2;                     // two consecutive rows
    int r1 = r0 + 1;

    int e0 = __builtin_nontemporal_load(&idx[r0]);
    int e1 = __builtin_nontemporal_load(&idx[r1]);

    const f32x4* __restrict__ s0 = tab4 + (size_t)e0 * 32 + col;
    const f32x4* __restrict__ s1 = tab4 + (size_t)e1 * 32 + col;
    f32x4* __restrict__ d0 = out4 + (size_t)r0 * 32 + col;
    f32x4* __restrict__ d1 = out4 + (size_t)r1 * 32 + col;

    // 8 independent gathers in flight
    f32x4 a0 = s0[0];
    f32x4 b0 = s0[8];
    f32x4 c0 = s0[16];
    f32x4 e0v = s0[24];
    f32x4 a1 = s1[0];
    f32x4 b1 = s1[8];
    f32x4 c1 = s1[16];
    f32x4 e1v = s1[24];

    __builtin_nontemporal_store(a0, &d0[0]);
    __builtin_nontemporal_store(b0, &d0[8]);
    __builtin_nontemporal_store(c0, &d0[16]);
    __builtin_nontemporal_store(e0v, &d0[24]);
    __builtin_nontemporal_store(a1, &d1[0]);
    __builtin_nontemporal_store(b1, &d1[8]);
    __builtin_nontemporal_store(c1, &d1[16]);
    __builtin_nontemporal_store(e1v, &d1[24]);
}

extern "C" void kernel_launch(void* const* d_in, const int* in_sizes, int n_in,
                              void* d_out, int out_size, void* d_ws, size_t ws_size,
                              hipStream_t stream) {
    const int* idx = (const int*)d_in[0];
    const f32x4* tab4 = (const f32x4*)d_in[1];
    f32x4* out4 = (f32x4*)d_out;

    // 65536 rows / 2 rows-per-thread * 8 threads-per-row = 262144 threads
    embed_gather_kernel<<<1024, 256, 0, stream>>>(idx, tab4, out4);
}